// Round 7
// baseline (288.617 us; speedup 1.0000x reference)
//
#include <hip/hip_runtime.h>
#include <stdint.h>
#include <stddef.h>

// Problem constants
#define B_   8
#define N_   8192
#define S_   2048
#define D_   256
#define M_   (B_*N_)     // 65536 total points
#define C0_  256         // MLP[0]
#define C1_  128         // MLP[1]
#define K2D_ 512         // 2*D
#define TS8_ 8           // S-segments (waves) per topk block
#define SEG8_ (S_/TS8_)  // 256
#define SWP_ 264         // padded LDS row stride (shorts) for W1 in gemm2

typedef __attribute__((ext_vector_type(8))) short short8;
typedef __attribute__((ext_vector_type(4))) float f32x4;
typedef __attribute__((ext_vector_type(2))) float f32x2;

__device__ __forceinline__ short f2bf(float f) {
  unsigned u = __float_as_uint(f);
  u += 0x7fffu + ((u >> 16) & 1u);   // round-to-nearest-even
  return (short)(u >> 16);
}
__device__ __forceinline__ float bf2f(short s) {
  return __uint_as_float(((unsigned)(unsigned short)s) << 16);
}

__device__ __forceinline__ void cp16(const void* g, void* l) {
  __builtin_amdgcn_global_load_lds(
      (__attribute__((address_space(1))) void*)(g),
      (__attribute__((address_space(3))) void*)(l), 16, 0, 0);
}

// Pack (d, idx): f64(d) has low 29 mantissa bits zero (exact f32 widen);
// OR the 11-bit index there. f64 numeric order == (d, idx) lex order for
// d >= 0. Unpack d via (float)p (rounds the idx bits away exactly).
__device__ __forceinline__ double packdi(float d, int s) {
  return __longlong_as_double(__double_as_longlong((double)d) |
                              (unsigned long long)(unsigned)s);
}

// 5-op sorted-3 insert (a0<=a1<=a2), pure min/max (v_min_f64/v_max_f64).
#define PINS(v)                                                               \
  {                                                                           \
    const double v_ = (v);                                                    \
    double t_ = fmax(a0, v_); a0 = fmin(a0, v_);                              \
    double u_ = fmax(a1, t_); a1 = fmin(a1, t_);                              \
    a2 = fmin(a2, u_);                                                        \
  }

// ---------------------------------------------------------------------------
// K0: convert W0/W1 to bf16; build component-SoA xyz2p; zero stats buffer.
// ---------------------------------------------------------------------------
__global__ void convw_kernel(const float* __restrict__ W0,
                             const float* __restrict__ W1,
                             const float* __restrict__ xyz2,
                             short* __restrict__ W0b, short* __restrict__ W1b,
                             float* __restrict__ xyz2p, float* __restrict__ stats) {
  int i = blockIdx.x * 256 + threadIdx.x;
  if (blockIdx.x == 0) {
    stats[threadIdx.x] = 0.f;
    stats[256 + threadIdx.x] = 0.f;
    stats[512 + threadIdx.x] = 0.f;
  }
  if (i < C0_ * K2D_) W0b[i] = f2bf(W0[i]);
  if (i < C1_ * C0_)  W1b[i] = f2bf(W1[i]);
  if (i < B_ * S_) {
    const int b = i >> 11, s = i & (S_ - 1);
    float x = xyz2[(size_t)i * 3 + 0];
    float y = xyz2[(size_t)i * 3 + 1];
    float z = xyz2[(size_t)i * 3 + 2];
    float ss = __fadd_rn(__fadd_rn(__fmul_rn(x, x), __fmul_rn(y, y)), __fmul_rn(z, z));
    float* xw = xyz2p + (size_t)b * 4 * S_;
    xw[s] = x; xw[S_ + s] = y; xw[2 * S_ + s] = z; xw[3 * S_ + s] = ss;
  }
}

// ---------------------------------------------------------------------------
// K1: top-3 NN (packed-f64 min/max) + sigmoid + fused interp.
// R7: phase-1 loads f32x2 -> f32x4 (4 candidates/iter, half the VMEM issues;
// per-element op order unchanged -> bit-identical selection).
// ---------------------------------------------------------------------------
__global__ __launch_bounds__(512, 8)
void topk_interp_kernel(const float* __restrict__ xyz1, const float* __restrict__ xyz2p,
                        const float* __restrict__ relw, const float* __restrict__ relb,
                        const float* __restrict__ p2, short* __restrict__ hi) {
  __shared__ double cdp[TS8_][64][3];
  __shared__ int   sj[64][3];
  __shared__ float sw[64][3];
  const int tid  = threadIdx.x;
  const int lane = tid & 63;
  const int seg  = __builtin_amdgcn_readfirstlane(tid >> 6);
  const int b    = blockIdx.x >> 7;
  const int n    = (blockIdx.x & 127) * 64 + lane;

  const float* p = xyz1 + ((size_t)b * N_ + n) * 3;
  const float ax = p[0], ay = p[1], az = p[2];
  const float s1 = __fadd_rn(__fadd_rn(__fmul_rn(ax, ax), __fmul_rn(ay, ay)), __fmul_rn(az, az));

  const float* xw = xyz2p + (size_t)b * 4 * S_;
  const f32x4* XP = (const f32x4*)(xw)           + seg * (SEG8_ / 4);
  const f32x4* YP = (const f32x4*)(xw + S_)      + seg * (SEG8_ / 4);
  const f32x4* ZP = (const f32x4*)(xw + 2 * S_)  + seg * (SEG8_ / 4);
  const f32x4* WP = (const f32x4*)(xw + 3 * S_)  + seg * (SEG8_ / 4);

  double a0 = 1e300, a1 = 1e300, a2 = 1e300;
  const int sbeg = seg * SEG8_;
  {
    #pragma clang fp contract(off)
    #pragma unroll 4
    for (int pr = 0; pr < SEG8_ / 4; pr++) {
      f32x4 X = XP[pr], Y = YP[pr], Z = ZP[pr], W = WP[pr];
      f32x4 t1 = ax * X;
      f32x4 t2 = ay * Y;
      f32x4 t3 = az * Z;
      f32x4 dt = (t1 + t2) + t3;
      f32x4 e  = s1 + W;
      f32x4 m  = 2.0f * dt;
      f32x4 d  = e - m;
      const int s = sbeg + 4 * pr;
      const float d0c = fmaxf(d.x, 0.f);
      const float d1c = fmaxf(d.y, 0.f);
      const float d2c = fmaxf(d.z, 0.f);
      const float d3c = fmaxf(d.w, 0.f);
      PINS(packdi(d0c, s));
      PINS(packdi(d1c, s + 1));
      PINS(packdi(d2c, s + 2));
      PINS(packdi(d3c, s + 3));
    }
  }
  cdp[seg][lane][0] = a0; cdp[seg][lane][1] = a1; cdp[seg][lane][2] = a2;
  __syncthreads();

  if (tid < 64) {
    double a0 = 1e300, a1 = 1e300, a2 = 1e300;
    #pragma unroll
    for (int sg = 0; sg < TS8_; sg++) {
      #pragma unroll
      for (int k = 0; k < 3; k++) {
        const double v = cdp[sg][tid][k];
        PINS(v);
      }
    }
    const float w0r = relw[0], w1r = relw[1], w2r = relw[2], w3r = relw[3], br = relb[0];
    const double pk[3] = {a0, a1, a2};
    #pragma unroll
    for (int k = 0; k < 3; k++) {
      const int s = (int)(__double_as_longlong(pk[k]) & 2047ULL);
      const float dk = (float)pk[k];   // exact d (idx bits round away)
      float ox = ax - xw[s], oy = ay - xw[S_ + s], oz = az - xw[2 * S_ + s];
      float t = dk * w0r + ox * w1r + oy * w2r + oz * w3r + br;
      float w = 1.0f / (1.0f + expf(-t));
      sj[tid][k] = s;
      sw[tid][k] = w * (1.0f / 3.0f);
    }
  }
  __syncthreads();

  // Phase 3: interp. 8 threads per row, 32 cols each (4 x short8 chunks).
  {
    const int r = tid >> 3;
    const int c0 = (tid & 7) * 32;
    const size_t rowg = (size_t)b * N_ + (size_t)(blockIdx.x & 127) * 64 + r;
    const int j0 = sj[r][0], j1 = sj[r][1], j2 = sj[r][2];
    const float w0 = sw[r][0], w1 = sw[r][1], w2 = sw[r][2];
    const float* pb = p2 + (size_t)b * S_ * D_ + c0;
    const float* q0 = pb + (size_t)j0 * D_;
    const float* q1 = pb + (size_t)j1 * D_;
    const float* q2 = pb + (size_t)j2 * D_;
    short* dst = hi + rowg * D_ + c0;
    #pragma unroll
    for (int cc = 0; cc < 32; cc += 8) {
      const float4 a0v = *(const float4*)(q0 + cc), e0 = *(const float4*)(q0 + cc + 4);
      const float4 a1v = *(const float4*)(q1 + cc), e1 = *(const float4*)(q1 + cc + 4);
      const float4 a2v = *(const float4*)(q2 + cc), e2 = *(const float4*)(q2 + cc + 4);
      float fv[8];
      fv[0] = w0 * a0v.x + w1 * a1v.x + w2 * a2v.x;
      fv[1] = w0 * a0v.y + w1 * a1v.y + w2 * a2v.y;
      fv[2] = w0 * a0v.z + w1 * a1v.z + w2 * a2v.z;
      fv[3] = w0 * a0v.w + w1 * a1v.w + w2 * a2v.w;
      fv[4] = w0 * e0.x + w1 * e1.x + w2 * e2.x;
      fv[5] = w0 * e0.y + w1 * e1.y + w2 * e2.y;
      fv[6] = w0 * e0.z + w1 * e1.z + w2 * e2.z;
      fv[7] = w0 * e0.w + w1 * e1.w + w2 * e2.w;
      short8 o;
      #pragma unroll
      for (int e = 0; e < 8; e++) o[e] = f2bf(fv[e]);
      *(short8*)(dst + cc) = o;
    }
  }
}

// ---------------------------------------------------------------------------
// GEMM1 (R7: no sB): a1[M][256](bf16) = [p1 | hi] @ W0^T.
// B-fragments read directly from L2-resident W0b (256 KB, shared by all
// blocks) as per-lane 16B loads — removes 2/3 of cp16 volume and the sB
// barrier-drain; compiler can hoist next-step B loads above the barrier
// (no LDS dependence). LDS = sA only (16 KB). A: k<256 from p1 (f32->bf16
// register path), k>=256 from hi via cp16. One barrier per k-step.
// ---------------------------------------------------------------------------
__global__ __launch_bounds__(256, 2)
void gemm1_kernel(const float* __restrict__ p1, const short* __restrict__ hi,
                  const short* __restrict__ Bw, const float* __restrict__ bias,
                  short* __restrict__ Cb, float* __restrict__ stats) {
  __shared__ __align__(16) short sA[2][128 * 32];
  const int tid = threadIdx.x;
  const int lane = tid & 63;
  const int wave = tid >> 6;
  const int wm = wave & 1;
  const int wn = wave >> 1;
  const size_t mbase = (size_t)(blockIdx.x & 7) * N_
                     + (size_t)(blockIdx.x >> 3) * 128;

  #define STAGE_A(K0, BUF)                                                    \
    if ((K0) < D_) {                                                          \
      _Pragma("unroll")                                                       \
      for (int t = 0; t < 2; t++) {                                           \
        const int c = tid * 2 + t;                                            \
        const int r = c >> 2; const int sc = (c & 3) * 8;                     \
        const float* src = p1 + (mbase + r) * D_ + (K0) + sc;                 \
        const float4 va = *(const float4*)src;                                \
        const float4 vb = *(const float4*)(src + 4);                          \
        short8 o;                                                             \
        o[0] = f2bf(va.x); o[1] = f2bf(va.y); o[2] = f2bf(va.z);              \
        o[3] = f2bf(va.w); o[4] = f2bf(vb.x); o[5] = f2bf(vb.y);              \
        o[6] = f2bf(vb.z); o[7] = f2bf(vb.w);                                 \
        *(short8*)&sA[BUF][r * 32 + sc] = o;                                  \
      }                                                                       \
    } else {                                                                  \
      _Pragma("unroll")                                                       \
      for (int t = 0; t < 2; t++) {                                           \
        const int ca = wave * 128 + t * 64 + lane;                            \
        cp16(hi + (mbase + (ca >> 2)) * D_ + ((K0) - D_) + (ca & 3) * 8,      \
             &sA[BUF][(wave * 128 + t * 64) * 8]);                            \
      }                                                                       \
    }

  f32x4 acc[4][8] = {};
  STAGE_A(0, 0);

  const int mr = lane & 15;
  const int ks = (lane >> 4) * 8;
  // Per-lane B base: row (wn*128 + mr), k-slice ks. Frag j adds j*16 rows.
  const short* Bbase = Bw + (size_t)(wn * 128 + mr) * K2D_ + ks;

  for (int k0 = 0, it = 0; k0 < K2D_; k0 += 32, it++) {
    __syncthreads();   // drains prev STAGE_A (vmcnt/lgkm) + WAR on sA bufs
    const int kn = k0 + 32;
    if (kn < K2D_) STAGE_A(kn, (it + 1) & 1);

    short8 af[4], bfr[8];
    #pragma unroll
    for (int j = 0; j < 8; j++)
      bfr[j] = *(const short8*)(Bbase + (size_t)j * 16 * K2D_ + k0);
    #pragma unroll
    for (int i = 0; i < 4; i++)
      af[i]  = *(const short8*)&sA[it & 1][(wm * 64 + i * 16 + mr) * 32 + ks];
    #pragma unroll
    for (int i = 0; i < 4; i++)
      #pragma unroll
      for (int j = 0; j < 8; j++)
        acc[i][j] = __builtin_amdgcn_mfma_f32_16x16x32_bf16(af[i], bfr[j], acc[i][j], 0, 0, 0);
  }
  #undef STAGE_A
  __syncthreads();   // all MFMA LDS reads done before sA reuse as sred

  // Epilogue: bf16 store + per-column (sum,sumsq) -> stats (bias excluded)
  const int cr = (lane >> 4) * 4;
  const int cc = lane & 15;
  float ps[8], ps2[8];
  #pragma unroll
  for (int j = 0; j < 8; j++) {
    const int col = wn * 128 + j * 16 + cc;
    const float bv = bias[col];
    float s = 0.f, s2 = 0.f;
    #pragma unroll
    for (int i = 0; i < 4; i++) {
      #pragma unroll
      for (int r = 0; r < 4; r++) {
        const float vv = acc[i][j][r];
        s += vv; s2 += vv * vv;
        const size_t row = mbase + wm * 64 + i * 16 + cr + r;
        Cb[row * C0_ + col] = f2bf(vv + bv);
      }
    }
    ps[j] = s; ps2[j] = s2;
  }
  #pragma unroll
  for (int j = 0; j < 8; j++) {
    ps[j]  += __shfl_xor(ps[j], 16);  ps[j]  += __shfl_xor(ps[j], 32);
    ps2[j] += __shfl_xor(ps2[j], 16); ps2[j] += __shfl_xor(ps2[j], 32);
  }
  float* sred = (float*)sA;   // reuse: 256 cols x {s,s2} = 2 KB
  if (wm == 1 && lane < 16) {
    #pragma unroll
    for (int j = 0; j < 8; j++) {
      const int c = wn * 128 + j * 16 + lane;
      sred[2 * c] = ps[j]; sred[2 * c + 1] = ps2[j];
    }
  }
  __syncthreads();
  if (wm == 0 && lane < 16) {
    #pragma unroll
    for (int j = 0; j < 8; j++) {
      const int c = wn * 128 + j * 16 + lane;
      atomicAdd(&stats[c],       ps[j]  + sred[2 * c]);
      atomicAdd(&stats[C0_ + c], ps2[j] + sred[2 * c + 1]);
    }
  }
}

// ---------------------------------------------------------------------------
// GEMM2 (+ BN-stats preamble): a2[M][128](bf16) = relu(bn(a1)) @ W1^T.
// ---------------------------------------------------------------------------
__global__ __launch_bounds__(256, 2)
void gemm2_kernel(const short* __restrict__ A, const short* __restrict__ Bw,
                  const float* __restrict__ st1,
                  const float* __restrict__ b0, const float* __restrict__ g0,
                  const float* __restrict__ be0,
                  const float* __restrict__ bias,
                  short* __restrict__ Cb, float* __restrict__ stats) {
  __shared__ __align__(16) short sW[C1_ * SWP_];  // 128 x 264 shorts = 66 KB
  __shared__ float sred[3 * 256];
  __shared__ __align__(16) float sss[2 * C0_];
  const int tid = threadIdx.x;
  const int lane = tid & 63;
  const int wave = tid >> 6;
  const size_t mbase = (size_t)blockIdx.x * 128;

  // Preamble: per-block BN scale/shift from global stats.
  {
    const float inv = 1.0f / (float)M_;
    const float m0 = st1[tid] * inv;
    const float var = st1[C0_ + tid] * inv - m0 * m0;
    const float mean = m0 + b0[tid];
    const float sc = g0[tid] * rsqrtf(var + 1e-5f);
    sss[tid] = sc;
    sss[C0_ + tid] = be0[tid] - mean * sc;
  }

  // Load all of W1b into padded LDS (coalesced 16B reads, manual ds_write)
  #pragma unroll
  for (int i = 0; i < 16; i++) {
    const int flat = i * 256 + tid;       // 16B-block index, 0..4095
    const int n = flat >> 5;              // W1 row (32 blocks of 8 shorts each)
    const int kb = flat & 31;
    *(short8*)&sW[n * SWP_ + kb * 8] = *(const short8*)(Bw + (size_t)flat * 8);
  }
  __syncthreads();

  f32x4 acc[2][8] = {};
  const int mr = lane & 15;
  const int ksq = (lane >> 4) * 8;

  for (int k0 = 0; k0 < C0_; k0 += 32) {
    const int kk = k0 + ksq;
    float4 sc0 = *(const float4*)&sss[kk];
    float4 sc1 = *(const float4*)&sss[kk + 4];
    float4 sh0 = *(const float4*)&sss[C0_ + kk];
    float4 sh1 = *(const float4*)&sss[C0_ + kk + 4];
    const float sc[8] = {sc0.x, sc0.y, sc0.z, sc0.w, sc1.x, sc1.y, sc1.z, sc1.w};
    const float sh[8] = {sh0.x, sh0.y, sh0.z, sh0.w, sh1.x, sh1.y, sh1.z, sh1.w};
    short8 af[2];
    #pragma unroll
    for (int i = 0; i < 2; i++) {
      const size_t row = mbase + wave * 32 + i * 16 + mr;
      short8 av = *(const short8*)(A + row * C0_ + kk);
      short8 o;
      #pragma unroll
      for (int e = 0; e < 8; e++) {
        float f = bf2f(av[e]) * sc[e] + sh[e];
        o[e] = f2bf(f > 0.f ? f : 0.f);
      }
      af[i] = o;
    }
    short8 bf8[8];
    #pragma unroll
    for (int j = 0; j < 8; j++) bf8[j] = *(const short8*)&sW[(j * 16 + mr) * SWP_ + kk];
    #pragma unroll
    for (int i = 0; i < 2; i++)
      #pragma unroll
      for (int j = 0; j < 8; j++)
        acc[i][j] = __builtin_amdgcn_mfma_f32_16x16x32_bf16(af[i], bf8[j], acc[i][j], 0, 0, 0);
  }

  // Epilogue: bf16 store + per-column (sum,sumsq) -> stats
  const int cr = (lane >> 4) * 4;
  const int cc = lane & 15;
  float ps[8], ps2[8];
  #pragma unroll
  for (int j = 0; j < 8; j++) {
    const int col = j * 16 + cc;
    const float bv = bias[col];
    float s = 0.f, s2 = 0.f;
    #pragma unroll
    for (int i = 0; i < 2; i++) {
      #pragma unroll
      for (int r = 0; r < 4; r++) {
        const float vv = acc[i][j][r];
        s += vv; s2 += vv * vv;
        const size_t row = mbase + wave * 32 + i * 16 + cr + r;
        Cb[row * C1_ + col] = f2bf(vv + bv);
      }
    }
    ps[j] = s; ps2[j] = s2;
  }
  #pragma unroll
  for (int j = 0; j < 8; j++) {
    ps[j]  += __shfl_xor(ps[j], 16);  ps[j]  += __shfl_xor(ps[j], 32);
    ps2[j] += __shfl_xor(ps2[j], 16); ps2[j] += __shfl_xor(ps2[j], 32);
  }
  if (wave > 0 && lane < 16) {
    #pragma unroll
    for (int j = 0; j < 8; j++) {
      const int c = j * 16 + lane;
      sred[(wave - 1) * 256 + c]       = ps[j];
      sred[(wave - 1) * 256 + 128 + c] = ps2[j];
    }
  }
  __syncthreads();
  if (wave == 0 && lane < 16) {
    #pragma unroll
    for (int j = 0; j < 8; j++) {
      const int c = j * 16 + lane;
      float s  = ps[j]  + sred[c]       + sred[256 + c]       + sred[512 + c];
      float s2 = ps2[j] + sred[128 + c] + sred[256 + 128 + c] + sred[512 + 128 + c];
      atomicAdd(&stats[c],       s);
      atomicAdd(&stats[C1_ + c], s2);
    }
  }
}

// ---------------------------------------------------------------------------
// norm2 (+ stats preamble): out(f32) = relu(a2*sc + sh), 8 elems/thread
// ---------------------------------------------------------------------------
__global__ __launch_bounds__(256, 1)
void norm2_kernel(const short* __restrict__ a2, const float* __restrict__ st2,
                  const float* __restrict__ b1, const float* __restrict__ g1,
                  const float* __restrict__ be1, float* __restrict__ out) {
  __shared__ __align__(16) float sss[2 * C1_];
  const int tid = threadIdx.x;
  if (tid < C1_) {
    const float inv = 1.0f / (float)M_;
    const float m0 = st2[tid] * inv;
    const float var = st2[C1_ + tid] * inv - m0 * m0;
    const float mean = m0 + b1[tid];
    const float sc = g1[tid] * rsqrtf(var + 1e-5f);
    sss[tid] = sc;
    sss[C1_ + tid] = be1[tid] - mean * sc;
  }
  __syncthreads();
  const size_t t = (size_t)blockIdx.x * 256 + tid;
  const size_t base = t * 8;
  const int c = (int)(base & (C1_ - 1));
  short8 v8 = *(const short8*)(a2 + base);
  float vv[8];
  #pragma unroll
  for (int k = 0; k < 8; k++) {
    float v = bf2f(v8[k]) * sss[c + k] + sss[C1_ + c + k];
    vv[k] = v > 0.f ? v : 0.f;
  }
  *(float4*)(out + base)     = make_float4(vv[0], vv[1], vv[2], vv[3]);
  *(float4*)(out + base + 4) = make_float4(vv[4], vv[5], vv[6], vv[7]);
}

// ---------------------------------------------------------------------------
// Launch
// ---------------------------------------------------------------------------
extern "C" void kernel_launch(void* const* d_in, const int* in_sizes, int n_in,
                              void* d_out, int out_size, void* d_ws, size_t ws_size,
                              hipStream_t stream) {
  const float* xyz1 = (const float*)d_in[0];
  const float* xyz2 = (const float*)d_in[1];
  const float* pts1 = (const float*)d_in[2];
  const float* pts2 = (const float*)d_in[3];
  const float* relw = (const float*)d_in[4];
  const float* relb = (const float*)d_in[5];
  const float* W0   = (const float*)d_in[6];
  const float* b0   = (const float*)d_in[7];
  const float* g0   = (const float*)d_in[8];
  const float* be0  = (const float*)d_in[9];
  const float* W1   = (const float*)d_in[10];
  const float* b1   = (const float*)d_in[11];
  const float* g1   = (const float*)d_in[12];
  const float* be1  = (const float*)d_in[13];

  char* ws = (char*)d_ws;
  constexpr size_t W0B_OFF = 0;                                    // 256*512 bf16
  constexpr size_t W1B_OFF = W0B_OFF + (size_t)C0_ * K2D_ * 2;     // 128*256 bf16
  constexpr size_t XW_OFF  = W1B_OFF + (size_t)C1_ * C0_ * 2;      // B*4*S f32
  constexpr size_t HI_OFF  = XW_OFF + (size_t)B_ * 4 * S_ * 4;     // M*256 bf16 (33.5 MB)
  constexpr size_t A1_OFF  = HI_OFF + (size_t)M_ * D_ * 2;         // M*256 bf16
  constexpr size_t A2_OFF  = A1_OFF + (size_t)M_ * C0_ * 2;        // M*128 bf16
  constexpr size_t ST_OFF  = A2_OFF + (size_t)M_ * C1_ * 2;        // 768 f32

  short* W0b   = (short*)(ws + W0B_OFF);
  short* W1b   = (short*)(ws + W1B_OFF);
  float* xyz2p = (float*)(ws + XW_OFF);
  short* hi    = (short*)(ws + HI_OFF);
  short* a1    = (short*)(ws + A1_OFF);
  short* a2    = (short*)(ws + A2_OFF);
  float* st    = (float*)(ws + ST_OFF);   // stats1 = st, stats2 = st + 512
  float* outp  = (float*)d_out;

  convw_kernel<<<512, 256, 0, stream>>>(W0, W1, xyz2, W0b, W1b, xyz2p, st);
  topk_interp_kernel<<<B_ * (N_ / 64), 512, 0, stream>>>(xyz1, xyz2p, relw, relb, pts2, hi);

  gemm1_kernel<<<M_ / 128, 256, 0, stream>>>(pts1, hi, W0b, b0, a1, st);
  gemm2_kernel<<<M_ / 128, 256, 0, stream>>>(a1, W1b, st, b0, g0, be0, b1, a2, st + 512);
  norm2_kernel<<<(size_t)M_ * C1_ / 8 / 256, 256, 0, stream>>>(a2, st + 512, b1, g1, be1, outp);
}

// Round 8
// 280.907 us; speedup vs baseline: 1.0274x; 1.0274x over previous
//
#include <hip/hip_runtime.h>
#include <stdint.h>
#include <stddef.h>

// Problem constants
#define B_   8
#define N_   8192
#define S_   2048
#define D_   256
#define M_   (B_*N_)     // 65536 total points
#define C0_  256         // MLP[0]
#define C1_  128         // MLP[1]
#define K2D_ 512         // 2*D
#define TS8_ 8           // S-segments (waves) per topk block
#define SEG8_ (S_/TS8_)  // 256
#define SWP_ 264         // padded LDS row stride (shorts) for W1 in gemm2

typedef __attribute__((ext_vector_type(8))) short short8;
typedef __attribute__((ext_vector_type(4))) float f32x4;
typedef __attribute__((ext_vector_type(2))) float f32x2;

__device__ __forceinline__ short f2bf(float f) {
  unsigned u = __float_as_uint(f);
  u += 0x7fffu + ((u >> 16) & 1u);   // round-to-nearest-even
  return (short)(u >> 16);
}
__device__ __forceinline__ float bf2f(short s) {
  return __uint_as_float(((unsigned)(unsigned short)s) << 16);
}

__device__ __forceinline__ void cp16(const void* g, void* l) {
  __builtin_amdgcn_global_load_lds(
      (__attribute__((address_space(1))) void*)(g),
      (__attribute__((address_space(3))) void*)(l), 16, 0, 0);
}

// Pack (d, idx): f64(d) has low 29 mantissa bits zero (exact f32 widen);
// OR the 11-bit index there. f64 numeric order == (d, idx) lex order for
// d >= 0. Unpack d via (float)p (idx bits are far below half-ULP -> exact).
__device__ __forceinline__ double packdi(float d, int s) {
  return __longlong_as_double(__double_as_longlong((double)d) |
                              (unsigned long long)(unsigned)s);
}

// 5-op sorted-3 insert (a0<=a1<=a2), pure min/max (v_min_f64/v_max_f64).
#define PINS(v)                                                               \
  {                                                                           \
    const double v_ = (v);                                                    \
    double t_ = fmax(a0, v_); a0 = fmin(a0, v_);                              \
    double u_ = fmax(a1, t_); a1 = fmin(a1, t_);                              \
    a2 = fmin(a2, u_);                                                        \
  }

// ---------------------------------------------------------------------------
// K0: convert W0/W1 to bf16; build component-SoA xyz2p; zero stats buffer.
// ---------------------------------------------------------------------------
__global__ void convw_kernel(const float* __restrict__ W0,
                             const float* __restrict__ W1,
                             const float* __restrict__ xyz2,
                             short* __restrict__ W0b, short* __restrict__ W1b,
                             float* __restrict__ xyz2p, float* __restrict__ stats) {
  int i = blockIdx.x * 256 + threadIdx.x;
  if (blockIdx.x == 0) {
    stats[threadIdx.x] = 0.f;
    stats[256 + threadIdx.x] = 0.f;
    stats[512 + threadIdx.x] = 0.f;
  }
  if (i < C0_ * K2D_) W0b[i] = f2bf(W0[i]);
  if (i < C1_ * C0_)  W1b[i] = f2bf(W1[i]);
  if (i < B_ * S_) {
    const int b = i >> 11, s = i & (S_ - 1);
    float x = xyz2[(size_t)i * 3 + 0];
    float y = xyz2[(size_t)i * 3 + 1];
    float z = xyz2[(size_t)i * 3 + 2];
    float ss = __fadd_rn(__fadd_rn(__fmul_rn(x, x), __fmul_rn(y, y)), __fmul_rn(z, z));
    float* xw = xyz2p + (size_t)b * 4 * S_;
    xw[s] = x; xw[S_ + s] = y; xw[2 * S_ + s] = z; xw[3 * S_ + s] = ss;
  }
}

// ---------------------------------------------------------------------------
// K1: top-3 NN (packed-f64 min/max) + sigmoid + fused interp.
// R8: wave-skip guard on the PINS network — run the 4x insert only when
// min4(d) <= (float)a2 (exact 3rd-best d; <= keeps equal-d/lower-idx ties
// so selection is exactly top_k). Skipped candidates have d strictly
// greater than the 3rd-best -> provably not in top-3.
// ---------------------------------------------------------------------------
__global__ __launch_bounds__(512, 8)
void topk_interp_kernel(const float* __restrict__ xyz1, const float* __restrict__ xyz2p,
                        const float* __restrict__ relw, const float* __restrict__ relb,
                        const float* __restrict__ p2, short* __restrict__ hi) {
  __shared__ double cdp[TS8_][64][3];
  __shared__ int   sj[64][3];
  __shared__ float sw[64][3];
  const int tid  = threadIdx.x;
  const int lane = tid & 63;
  const int seg  = __builtin_amdgcn_readfirstlane(tid >> 6);
  const int b    = blockIdx.x >> 7;
  const int n    = (blockIdx.x & 127) * 64 + lane;

  const float* p = xyz1 + ((size_t)b * N_ + n) * 3;
  const float ax = p[0], ay = p[1], az = p[2];
  const float s1 = __fadd_rn(__fadd_rn(__fmul_rn(ax, ax), __fmul_rn(ay, ay)), __fmul_rn(az, az));

  const float* xw = xyz2p + (size_t)b * 4 * S_;
  const f32x4* XP = (const f32x4*)(xw)           + seg * (SEG8_ / 4);
  const f32x4* YP = (const f32x4*)(xw + S_)      + seg * (SEG8_ / 4);
  const f32x4* ZP = (const f32x4*)(xw + 2 * S_)  + seg * (SEG8_ / 4);
  const f32x4* WP = (const f32x4*)(xw + 3 * S_)  + seg * (SEG8_ / 4);

  double a0 = 1e300, a1 = 1e300, a2 = 1e300;
  float athr = 3.4e38f;              // f32 view of a2's distance
  const int sbeg = seg * SEG8_;
  {
    #pragma clang fp contract(off)
    #pragma unroll 4
    for (int pr = 0; pr < SEG8_ / 4; pr++) {
      f32x4 X = XP[pr], Y = YP[pr], Z = ZP[pr], W = WP[pr];
      f32x4 t1 = ax * X;
      f32x4 t2 = ay * Y;
      f32x4 t3 = az * Z;
      f32x4 dt = (t1 + t2) + t3;
      f32x4 e  = s1 + W;
      f32x4 m  = 2.0f * dt;
      f32x4 d  = e - m;
      const int s = sbeg + 4 * pr;
      const float d0c = fmaxf(d.x, 0.f);
      const float d1c = fmaxf(d.y, 0.f);
      const float d2c = fmaxf(d.z, 0.f);
      const float d3c = fmaxf(d.w, 0.f);
      const float mn4 = fminf(fminf(d0c, d1c), fminf(d2c, d3c));
      if (mn4 <= athr) {
        PINS(packdi(d0c, s));
        PINS(packdi(d1c, s + 1));
        PINS(packdi(d2c, s + 2));
        PINS(packdi(d3c, s + 3));
        athr = (float)a2;            // exact d of 3rd best (idx bits round away)
      }
    }
  }
  cdp[seg][lane][0] = a0; cdp[seg][lane][1] = a1; cdp[seg][lane][2] = a2;
  __syncthreads();

  if (tid < 64) {
    double a0 = 1e300, a1 = 1e300, a2 = 1e300;
    #pragma unroll
    for (int sg = 0; sg < TS8_; sg++) {
      #pragma unroll
      for (int k = 0; k < 3; k++) {
        const double v = cdp[sg][tid][k];
        PINS(v);
      }
    }
    const float w0r = relw[0], w1r = relw[1], w2r = relw[2], w3r = relw[3], br = relb[0];
    const double pk[3] = {a0, a1, a2};
    #pragma unroll
    for (int k = 0; k < 3; k++) {
      const int s = (int)(__double_as_longlong(pk[k]) & 2047ULL);
      const float dk = (float)pk[k];   // exact d (idx bits round away)
      float ox = ax - xw[s], oy = ay - xw[S_ + s], oz = az - xw[2 * S_ + s];
      float t = dk * w0r + ox * w1r + oy * w2r + oz * w3r + br;
      float w = 1.0f / (1.0f + expf(-t));
      sj[tid][k] = s;
      sw[tid][k] = w * (1.0f / 3.0f);
    }
  }
  __syncthreads();

  // Phase 3: interp. 8 threads per row, 32 cols each (4 x short8 chunks).
  {
    const int r = tid >> 3;
    const int c0 = (tid & 7) * 32;
    const size_t rowg = (size_t)b * N_ + (size_t)(blockIdx.x & 127) * 64 + r;
    const int j0 = sj[r][0], j1 = sj[r][1], j2 = sj[r][2];
    const float w0 = sw[r][0], w1 = sw[r][1], w2 = sw[r][2];
    const float* pb = p2 + (size_t)b * S_ * D_ + c0;
    const float* q0 = pb + (size_t)j0 * D_;
    const float* q1 = pb + (size_t)j1 * D_;
    const float* q2 = pb + (size_t)j2 * D_;
    short* dst = hi + rowg * D_ + c0;
    #pragma unroll
    for (int cc = 0; cc < 32; cc += 8) {
      const float4 a0v = *(const float4*)(q0 + cc), e0 = *(const float4*)(q0 + cc + 4);
      const float4 a1v = *(const float4*)(q1 + cc), e1 = *(const float4*)(q1 + cc + 4);
      const float4 a2v = *(const float4*)(q2 + cc), e2 = *(const float4*)(q2 + cc + 4);
      float fv[8];
      fv[0] = w0 * a0v.x + w1 * a1v.x + w2 * a2v.x;
      fv[1] = w0 * a0v.y + w1 * a1v.y + w2 * a2v.y;
      fv[2] = w0 * a0v.z + w1 * a1v.z + w2 * a2v.z;
      fv[3] = w0 * a0v.w + w1 * a1v.w + w2 * a2v.w;
      fv[4] = w0 * e0.x + w1 * e1.x + w2 * e2.x;
      fv[5] = w0 * e0.y + w1 * e1.y + w2 * e2.y;
      fv[6] = w0 * e0.z + w1 * e1.z + w2 * e2.z;
      fv[7] = w0 * e0.w + w1 * e1.w + w2 * e2.w;
      short8 o;
      #pragma unroll
      for (int e = 0; e < 8; e++) o[e] = f2bf(fv[e]);
      *(short8*)(dst + cc) = o;
    }
  }
}

// ---------------------------------------------------------------------------
// GEMM1 (R8: reverted to R6 structure): a1[M][256](bf16) = [p1 | hi] @ W0^T.
// 128x256 tile, BK=32, double-buffered sA+sB. A: k<256 from p1 (f32->bf16
// register path), k>=256 from hi via cp16. B: 1024-chunk cp16 (prefetched
// one step ahead — R7 proved in-step B loads from L2 are latency-exposed).
// One barrier per k-step.
// ---------------------------------------------------------------------------
__global__ __launch_bounds__(256, 2)
void gemm1_kernel(const float* __restrict__ p1, const short* __restrict__ hi,
                  const short* __restrict__ Bw, const float* __restrict__ bias,
                  short* __restrict__ Cb, float* __restrict__ stats) {
  __shared__ __align__(16) short sA[2][128 * 32];
  __shared__ __align__(16) short sB[2][256 * 32];
  const int tid = threadIdx.x;
  const int lane = tid & 63;
  const int wave = tid >> 6;
  const int wm = wave & 1;
  const int wn = wave >> 1;
  const size_t mbase = (size_t)(blockIdx.x & 7) * N_
                     + (size_t)(blockIdx.x >> 3) * 128;

  #define STAGE_A(K0, BUF)                                                    \
    if ((K0) < D_) {                                                          \
      _Pragma("unroll")                                                       \
      for (int t = 0; t < 2; t++) {                                           \
        const int c = tid * 2 + t;                                            \
        const int r = c >> 2; const int sc = (c & 3) * 8;                     \
        const float* src = p1 + (mbase + r) * D_ + (K0) + sc;                 \
        const float4 va = *(const float4*)src;                                \
        const float4 vb = *(const float4*)(src + 4);                          \
        short8 o;                                                             \
        o[0] = f2bf(va.x); o[1] = f2bf(va.y); o[2] = f2bf(va.z);              \
        o[3] = f2bf(va.w); o[4] = f2bf(vb.x); o[5] = f2bf(vb.y);              \
        o[6] = f2bf(vb.z); o[7] = f2bf(vb.w);                                 \
        *(short8*)&sA[BUF][r * 32 + sc] = o;                                  \
      }                                                                       \
    } else {                                                                  \
      _Pragma("unroll")                                                       \
      for (int t = 0; t < 2; t++) {                                           \
        const int ca = wave * 128 + t * 64 + lane;                            \
        cp16(hi + (mbase + (ca >> 2)) * D_ + ((K0) - D_) + (ca & 3) * 8,      \
             &sA[BUF][(wave * 128 + t * 64) * 8]);                            \
      }                                                                       \
    }

  #define STAGE_B(K0, BUF)                                                    \
    _Pragma("unroll")                                                         \
    for (int t = 0; t < 4; t++) {                                             \
      const int cb = wave * 256 + t * 64 + lane;                              \
      cp16(Bw + (size_t)(cb >> 2) * K2D_ + (K0) + (cb & 3) * 8,               \
           &sB[BUF][(wave * 256 + t * 64) * 8]);                              \
    }

  f32x4 acc[4][8] = {};
  STAGE_A(0, 0);
  STAGE_B(0, 0);

  const int mr = lane & 15;
  const int ks = (lane >> 4) * 8;

  for (int k0 = 0, it = 0; k0 < K2D_; k0 += 32, it++) {
    __syncthreads();   // drains prev STAGE (vmcnt0 + lgkm) + WAR on LDS bufs
    const int kn = k0 + 32;
    if (kn < K2D_) {
      STAGE_A(kn, (it + 1) & 1);
      STAGE_B(kn, (it + 1) & 1);
    }

    short8 af[4], bfr[8];
    #pragma unroll
    for (int i = 0; i < 4; i++)
      af[i]  = *(const short8*)&sA[it & 1][(wm * 64 + i * 16 + mr) * 32 + ks];
    #pragma unroll
    for (int j = 0; j < 8; j++)
      bfr[j] = *(const short8*)&sB[it & 1][(wn * 128 + j * 16 + mr) * 32 + ks];
    #pragma unroll
    for (int i = 0; i < 4; i++)
      #pragma unroll
      for (int j = 0; j < 8; j++)
        acc[i][j] = __builtin_amdgcn_mfma_f32_16x16x32_bf16(af[i], bfr[j], acc[i][j], 0, 0, 0);
  }
  #undef STAGE_A
  #undef STAGE_B
  __syncthreads();   // all MFMA LDS reads done before sA reuse as sred

  // Epilogue: bf16 store + per-column (sum,sumsq) -> stats (bias excluded)
  const int cr = (lane >> 4) * 4;
  const int cc = lane & 15;
  float ps[8], ps2[8];
  #pragma unroll
  for (int j = 0; j < 8; j++) {
    const int col = wn * 128 + j * 16 + cc;
    const float bv = bias[col];
    float s = 0.f, s2 = 0.f;
    #pragma unroll
    for (int i = 0; i < 4; i++) {
      #pragma unroll
      for (int r = 0; r < 4; r++) {
        const float vv = acc[i][j][r];
        s += vv; s2 += vv * vv;
        const size_t row = mbase + wm * 64 + i * 16 + cr + r;
        Cb[row * C0_ + col] = f2bf(vv + bv);
      }
    }
    ps[j] = s; ps2[j] = s2;
  }
  #pragma unroll
  for (int j = 0; j < 8; j++) {
    ps[j]  += __shfl_xor(ps[j], 16);  ps[j]  += __shfl_xor(ps[j], 32);
    ps2[j] += __shfl_xor(ps2[j], 16); ps2[j] += __shfl_xor(ps2[j], 32);
  }
  float* sred = (float*)sA;   // reuse: 256 cols x {s,s2} = 2 KB
  if (wm == 1 && lane < 16) {
    #pragma unroll
    for (int j = 0; j < 8; j++) {
      const int c = wn * 128 + j * 16 + lane;
      sred[2 * c] = ps[j]; sred[2 * c + 1] = ps2[j];
    }
  }
  __syncthreads();
  if (wm == 0 && lane < 16) {
    #pragma unroll
    for (int j = 0; j < 8; j++) {
      const int c = wn * 128 + j * 16 + lane;
      atomicAdd(&stats[c],       ps[j]  + sred[2 * c]);
      atomicAdd(&stats[C0_ + c], ps2[j] + sred[2 * c + 1]);
    }
  }
}

// ---------------------------------------------------------------------------
// GEMM2 (+ BN-stats preamble): a2[M][128](bf16) = relu(bn(a1)) @ W1^T.
// ---------------------------------------------------------------------------
__global__ __launch_bounds__(256, 2)
void gemm2_kernel(const short* __restrict__ A, const short* __restrict__ Bw,
                  const float* __restrict__ st1,
                  const float* __restrict__ b0, const float* __restrict__ g0,
                  const float* __restrict__ be0,
                  const float* __restrict__ bias,
                  short* __restrict__ Cb, float* __restrict__ stats) {
  __shared__ __align__(16) short sW[C1_ * SWP_];  // 128 x 264 shorts = 66 KB
  __shared__ float sred[3 * 256];
  __shared__ __align__(16) float sss[2 * C0_];
  const int tid = threadIdx.x;
  const int lane = tid & 63;
  const int wave = tid >> 6;
  const size_t mbase = (size_t)blockIdx.x * 128;

  // Preamble: per-block BN scale/shift from global stats.
  {
    const float inv = 1.0f / (float)M_;
    const float m0 = st1[tid] * inv;
    const float var = st1[C0_ + tid] * inv - m0 * m0;
    const float mean = m0 + b0[tid];
    const float sc = g0[tid] * rsqrtf(var + 1e-5f);
    sss[tid] = sc;
    sss[C0_ + tid] = be0[tid] - mean * sc;
  }

  // Load all of W1b into padded LDS (coalesced 16B reads, manual ds_write)
  #pragma unroll
  for (int i = 0; i < 16; i++) {
    const int flat = i * 256 + tid;       // 16B-block index, 0..4095
    const int n = flat >> 5;              // W1 row (32 blocks of 8 shorts each)
    const int kb = flat & 31;
    *(short8*)&sW[n * SWP_ + kb * 8] = *(const short8*)(Bw + (size_t)flat * 8);
  }
  __syncthreads();

  f32x4 acc[2][8] = {};
  const int mr = lane & 15;
  const int ksq = (lane >> 4) * 8;

  for (int k0 = 0; k0 < C0_; k0 += 32) {
    const int kk = k0 + ksq;
    float4 sc0 = *(const float4*)&sss[kk];
    float4 sc1 = *(const float4*)&sss[kk + 4];
    float4 sh0 = *(const float4*)&sss[C0_ + kk];
    float4 sh1 = *(const float4*)&sss[C0_ + kk + 4];
    const float sc[8] = {sc0.x, sc0.y, sc0.z, sc0.w, sc1.x, sc1.y, sc1.z, sc1.w};
    const float sh[8] = {sh0.x, sh0.y, sh0.z, sh0.w, sh1.x, sh1.y, sh1.z, sh1.w};
    short8 af[2];
    #pragma unroll
    for (int i = 0; i < 2; i++) {
      const size_t row = mbase + wave * 32 + i * 16 + mr;
      short8 av = *(const short8*)(A + row * C0_ + kk);
      short8 o;
      #pragma unroll
      for (int e = 0; e < 8; e++) {
        float f = bf2f(av[e]) * sc[e] + sh[e];
        o[e] = f2bf(f > 0.f ? f : 0.f);
      }
      af[i] = o;
    }
    short8 bf8[8];
    #pragma unroll
    for (int j = 0; j < 8; j++) bf8[j] = *(const short8*)&sW[(j * 16 + mr) * SWP_ + kk];
    #pragma unroll
    for (int i = 0; i < 2; i++)
      #pragma unroll
      for (int j = 0; j < 8; j++)
        acc[i][j] = __builtin_amdgcn_mfma_f32_16x16x32_bf16(af[i], bf8[j], acc[i][j], 0, 0, 0);
  }

  // Epilogue: bf16 store + per-column (sum,sumsq) -> stats
  const int cr = (lane >> 4) * 4;
  const int cc = lane & 15;
  float ps[8], ps2[8];
  #pragma unroll
  for (int j = 0; j < 8; j++) {
    const int col = j * 16 + cc;
    const float bv = bias[col];
    float s = 0.f, s2 = 0.f;
    #pragma unroll
    for (int i = 0; i < 2; i++) {
      #pragma unroll
      for (int r = 0; r < 4; r++) {
        const float vv = acc[i][j][r];
        s += vv; s2 += vv * vv;
        const size_t row = mbase + wave * 32 + i * 16 + cr + r;
        Cb[row * C1_ + col] = f2bf(vv + bv);
      }
    }
    ps[j] = s; ps2[j] = s2;
  }
  #pragma unroll
  for (int j = 0; j < 8; j++) {
    ps[j]  += __shfl_xor(ps[j], 16);  ps[j]  += __shfl_xor(ps[j], 32);
    ps2[j] += __shfl_xor(ps2[j], 16); ps2[j] += __shfl_xor(ps2[j], 32);
  }
  if (wave > 0 && lane < 16) {
    #pragma unroll
    for (int j = 0; j < 8; j++) {
      const int c = j * 16 + lane;
      sred[(wave - 1) * 256 + c]       = ps[j];
      sred[(wave - 1) * 256 + 128 + c] = ps2[j];
    }
  }
  __syncthreads();
  if (wave == 0 && lane < 16) {
    #pragma unroll
    for (int j = 0; j < 8; j++) {
      const int c = j * 16 + lane;
      float s  = ps[j]  + sred[c]       + sred[256 + c]       + sred[512 + c];
      float s2 = ps2[j] + sred[128 + c] + sred[256 + 128 + c] + sred[512 + 128 + c];
      atomicAdd(&stats[c],       s);
      atomicAdd(&stats[C1_ + c], s2);
    }
  }
}

// ---------------------------------------------------------------------------
// norm2 (+ stats preamble): out(f32) = relu(a2*sc + sh), 8 elems/thread
// ---------------------------------------------------------------------------
__global__ __launch_bounds__(256, 1)
void norm2_kernel(const short* __restrict__ a2, const float* __restrict__ st2,
                  const float* __restrict__ b1, const float* __restrict__ g1,
                  const float* __restrict__ be1, float* __restrict__ out) {
  __shared__ __align__(16) float sss[2 * C1_];
  const int tid = threadIdx.x;
  if (tid < C1_) {
    const float inv = 1.0f / (float)M_;
    const float m0 = st2[tid] * inv;
    const float var = st2[C1_ + tid] * inv - m0 * m0;
    const float mean = m0 + b1[tid];
    const float sc = g1[tid] * rsqrtf(var + 1e-5f);
    sss[tid] = sc;
    sss[C1_ + tid] = be1[tid] - mean * sc;
  }
  __syncthreads();
  const size_t t = (size_t)blockIdx.x * 256 + tid;
  const size_t base = t * 8;
  const int c = (int)(base & (C1_ - 1));
  short8 v8 = *(const short8*)(a2 + base);
  float vv[8];
  #pragma unroll
  for (int k = 0; k < 8; k++) {
    float v = bf2f(v8[k]) * sss[c + k] + sss[C1_ + c + k];
    vv[k] = v > 0.f ? v : 0.f;
  }
  *(float4*)(out + base)     = make_float4(vv[0], vv[1], vv[2], vv[3]);
  *(float4*)(out + base + 4) = make_float4(vv[4], vv[5], vv[6], vv[7]);
}

// ---------------------------------------------------------------------------
// Launch
// ---------------------------------------------------------------------------
extern "C" void kernel_launch(void* const* d_in, const int* in_sizes, int n_in,
                              void* d_out, int out_size, void* d_ws, size_t ws_size,
                              hipStream_t stream) {
  const float* xyz1 = (const float*)d_in[0];
  const float* xyz2 = (const float*)d_in[1];
  const float* pts1 = (const float*)d_in[2];
  const float* pts2 = (const float*)d_in[3];
  const float* relw = (const float*)d_in[4];
  const float* relb = (const float*)d_in[5];
  const float* W0   = (const float*)d_in[6];
  const float* b0   = (const float*)d_in[7];
  const float* g0   = (const float*)d_in[8];
  const float* be0  = (const float*)d_in[9];
  const float* W1   = (const float*)d_in[10];
  const float* b1   = (const float*)d_in[11];
  const float* g1   = (const float*)d_in[12];
  const float* be1  = (const float*)d_in[13];

  char* ws = (char*)d_ws;
  constexpr size_t W0B_OFF = 0;                                    // 256*512 bf16
  constexpr size_t W1B_OFF = W0B_OFF + (size_t)C0_ * K2D_ * 2;     // 128*256 bf16
  constexpr size_t XW_OFF  = W1B_OFF + (size_t)C1_ * C0_ * 2;      // B*4*S f32
  constexpr size_t HI_OFF  = XW_OFF + (size_t)B_ * 4 * S_ * 4;     // M*256 bf16 (33.5 MB)
  constexpr size_t A1_OFF  = HI_OFF + (size_t)M_ * D_ * 2;         // M*256 bf16
  constexpr size_t A2_OFF  = A1_OFF + (size_t)M_ * C0_ * 2;        // M*128 bf16
  constexpr size_t ST_OFF  = A2_OFF + (size_t)M_ * C1_ * 2;        // 768 f32

  short* W0b   = (short*)(ws + W0B_OFF);
  short* W1b   = (short*)(ws + W1B_OFF);
  float* xyz2p = (float*)(ws + XW_OFF);
  short* hi    = (short*)(ws + HI_OFF);
  short* a1    = (short*)(ws + A1_OFF);
  short* a2    = (short*)(ws + A2_OFF);
  float* st    = (float*)(ws + ST_OFF);   // stats1 = st, stats2 = st + 512
  float* outp  = (float*)d_out;

  convw_kernel<<<512, 256, 0, stream>>>(W0, W1, xyz2, W0b, W1b, xyz2p, st);
  topk_interp_kernel<<<B_ * (N_ / 64), 512, 0, stream>>>(xyz1, xyz2p, relw, relb, pts2, hi);

  gemm1_kernel<<<M_ / 128, 256, 0, stream>>>(pts1, hi, W0b, b0, a1, st);
  gemm2_kernel<<<M_ / 128, 256, 0, stream>>>(a1, W1b, st, b0, g0, be0, b1, a2, st + 512);
  norm2_kernel<<<(size_t)M_ * C1_ / 8 / 256, 256, 0, stream>>>(a2, st + 512, b1, g1, be1, outp);
}

// Round 9
// 275.337 us; speedup vs baseline: 1.0482x; 1.0202x over previous
//
#include <hip/hip_runtime.h>
#include <stdint.h>
#include <stddef.h>

// Problem constants
#define B_   8
#define N_   8192
#define S_   2048
#define D_   256
#define M_   (B_*N_)     // 65536 total points
#define C0_  256         // MLP[0]
#define C1_  128         // MLP[1]
#define K2D_ 512         // 2*D
#define TS8_ 8           // S-segments (waves) per topk block
#define SEG8_ (S_/TS8_)  // 256
#define SWP_ 264         // padded LDS row stride (shorts) for W1 in gemm2

typedef __attribute__((ext_vector_type(8))) short short8;
typedef __attribute__((ext_vector_type(4))) float f32x4;
typedef __attribute__((ext_vector_type(2))) float f32x2;

__device__ __forceinline__ short f2bf(float f) {
  unsigned u = __float_as_uint(f);
  u += 0x7fffu + ((u >> 16) & 1u);   // round-to-nearest-even
  return (short)(u >> 16);
}
__device__ __forceinline__ float bf2f(short s) {
  return __uint_as_float(((unsigned)(unsigned short)s) << 16);
}

__device__ __forceinline__ void cp16(const void* g, void* l) {
  __builtin_amdgcn_global_load_lds(
      (__attribute__((address_space(1))) void*)(g),
      (__attribute__((address_space(3))) void*)(l), 16, 0, 0);
}

// Pack (d, idx): f64(d) has low 29 mantissa bits zero (exact f32 widen);
// OR the 11-bit index there. f64 numeric order == (d, idx) lex order for
// d >= 0. Unpack d via (float)p (idx bits are far below half-ULP -> exact).
__device__ __forceinline__ double packdi(float d, int s) {
  return __longlong_as_double(__double_as_longlong((double)d) |
                              (unsigned long long)(unsigned)s);
}

// 5-op sorted-3 insert (a0<=a1<=a2), pure min/max (v_min_f64/v_max_f64).
#define PINS(v)                                                               \
  {                                                                           \
    const double v_ = (v);                                                    \
    double t_ = fmax(a0, v_); a0 = fmin(a0, v_);                              \
    double u_ = fmax(a1, t_); a1 = fmin(a1, t_);                              \
    a2 = fmin(a2, u_);                                                        \
  }

// ---------------------------------------------------------------------------
// K0: convert W0/W1 to bf16; build component-SoA xyz2p; zero stats buffer.
// ---------------------------------------------------------------------------
__global__ void convw_kernel(const float* __restrict__ W0,
                             const float* __restrict__ W1,
                             const float* __restrict__ xyz2,
                             short* __restrict__ W0b, short* __restrict__ W1b,
                             float* __restrict__ xyz2p, float* __restrict__ stats) {
  int i = blockIdx.x * 256 + threadIdx.x;
  if (blockIdx.x == 0) {
    stats[threadIdx.x] = 0.f;
    stats[256 + threadIdx.x] = 0.f;
    stats[512 + threadIdx.x] = 0.f;
  }
  if (i < C0_ * K2D_) W0b[i] = f2bf(W0[i]);
  if (i < C1_ * C0_)  W1b[i] = f2bf(W1[i]);
  if (i < B_ * S_) {
    const int b = i >> 11, s = i & (S_ - 1);
    float x = xyz2[(size_t)i * 3 + 0];
    float y = xyz2[(size_t)i * 3 + 1];
    float z = xyz2[(size_t)i * 3 + 2];
    float ss = __fadd_rn(__fadd_rn(__fmul_rn(x, x), __fmul_rn(y, y)), __fmul_rn(z, z));
    float* xw = xyz2p + (size_t)b * 4 * S_;
    xw[s] = x; xw[S_ + s] = y; xw[2 * S_ + s] = z; xw[3 * S_ + s] = ss;
  }
}

// ---------------------------------------------------------------------------
// K1: top-3 NN (packed-f64 min/max) + sigmoid + fused interp.
// R9: reverted to R6-exact scan (f32x2 loads, unconditional PINS) — R8's
// wave-skip guard was null-to-negative (83 -> 85 us); PINS is the floor.
// ---------------------------------------------------------------------------
__global__ __launch_bounds__(512, 8)
void topk_interp_kernel(const float* __restrict__ xyz1, const float* __restrict__ xyz2p,
                        const float* __restrict__ relw, const float* __restrict__ relb,
                        const float* __restrict__ p2, short* __restrict__ hi) {
  __shared__ double cdp[TS8_][64][3];
  __shared__ int   sj[64][3];
  __shared__ float sw[64][3];
  const int tid  = threadIdx.x;
  const int lane = tid & 63;
  const int seg  = __builtin_amdgcn_readfirstlane(tid >> 6);
  const int b    = blockIdx.x >> 7;
  const int n    = (blockIdx.x & 127) * 64 + lane;

  const float* p = xyz1 + ((size_t)b * N_ + n) * 3;
  const float ax = p[0], ay = p[1], az = p[2];
  const float s1 = __fadd_rn(__fadd_rn(__fmul_rn(ax, ax), __fmul_rn(ay, ay)), __fmul_rn(az, az));

  const float* xw = xyz2p + (size_t)b * 4 * S_;
  const f32x2* XP = (const f32x2*)(xw)           + seg * (SEG8_ / 2);
  const f32x2* YP = (const f32x2*)(xw + S_)      + seg * (SEG8_ / 2);
  const f32x2* ZP = (const f32x2*)(xw + 2 * S_)  + seg * (SEG8_ / 2);
  const f32x2* WP = (const f32x2*)(xw + 3 * S_)  + seg * (SEG8_ / 2);

  double a0 = 1e300, a1 = 1e300, a2 = 1e300;
  const int sbeg = seg * SEG8_;
  {
    #pragma clang fp contract(off)
    #pragma unroll 4
    for (int pr = 0; pr < SEG8_ / 2; pr++) {
      f32x2 X = XP[pr], Y = YP[pr], Z = ZP[pr], W = WP[pr];
      f32x2 t1 = ax * X;
      f32x2 t2 = ay * Y;
      f32x2 t3 = az * Z;
      f32x2 dt = (t1 + t2) + t3;
      f32x2 e  = s1 + W;
      f32x2 m  = 2.0f * dt;
      f32x2 d  = e - m;
      const float dlo = fmaxf(d.x, 0.f), dhi = fmaxf(d.y, 0.f);
      const int s = sbeg + 2 * pr;
      const double p0 = packdi(dlo, s);
      const double p1 = packdi(dhi, s + 1);
      PINS(p0);
      PINS(p1);
    }
  }
  cdp[seg][lane][0] = a0; cdp[seg][lane][1] = a1; cdp[seg][lane][2] = a2;
  __syncthreads();

  if (tid < 64) {
    double a0 = 1e300, a1 = 1e300, a2 = 1e300;
    #pragma unroll
    for (int sg = 0; sg < TS8_; sg++) {
      #pragma unroll
      for (int k = 0; k < 3; k++) {
        const double v = cdp[sg][tid][k];
        PINS(v);
      }
    }
    const float w0r = relw[0], w1r = relw[1], w2r = relw[2], w3r = relw[3], br = relb[0];
    const double pk[3] = {a0, a1, a2};
    #pragma unroll
    for (int k = 0; k < 3; k++) {
      const int s = (int)(__double_as_longlong(pk[k]) & 2047ULL);
      const float dk = (float)pk[k];   // exact d (idx bits round away)
      float ox = ax - xw[s], oy = ay - xw[S_ + s], oz = az - xw[2 * S_ + s];
      float t = dk * w0r + ox * w1r + oy * w2r + oz * w3r + br;
      float w = 1.0f / (1.0f + expf(-t));
      sj[tid][k] = s;
      sw[tid][k] = w * (1.0f / 3.0f);
    }
  }
  __syncthreads();

  // Phase 3: interp. 8 threads per row, 32 cols each (4 x short8 chunks).
  {
    const int r = tid >> 3;
    const int c0 = (tid & 7) * 32;
    const size_t rowg = (size_t)b * N_ + (size_t)(blockIdx.x & 127) * 64 + r;
    const int j0 = sj[r][0], j1 = sj[r][1], j2 = sj[r][2];
    const float w0 = sw[r][0], w1 = sw[r][1], w2 = sw[r][2];
    const float* pb = p2 + (size_t)b * S_ * D_ + c0;
    const float* q0 = pb + (size_t)j0 * D_;
    const float* q1 = pb + (size_t)j1 * D_;
    const float* q2 = pb + (size_t)j2 * D_;
    short* dst = hi + rowg * D_ + c0;
    #pragma unroll
    for (int cc = 0; cc < 32; cc += 8) {
      const float4 a0v = *(const float4*)(q0 + cc), e0 = *(const float4*)(q0 + cc + 4);
      const float4 a1v = *(const float4*)(q1 + cc), e1 = *(const float4*)(q1 + cc + 4);
      const float4 a2v = *(const float4*)(q2 + cc), e2 = *(const float4*)(q2 + cc + 4);
      float fv[8];
      fv[0] = w0 * a0v.x + w1 * a1v.x + w2 * a2v.x;
      fv[1] = w0 * a0v.y + w1 * a1v.y + w2 * a2v.y;
      fv[2] = w0 * a0v.z + w1 * a1v.z + w2 * a2v.z;
      fv[3] = w0 * a0v.w + w1 * a1v.w + w2 * a2v.w;
      fv[4] = w0 * e0.x + w1 * e1.x + w2 * e2.x;
      fv[5] = w0 * e0.y + w1 * e1.y + w2 * e2.y;
      fv[6] = w0 * e0.z + w1 * e1.z + w2 * e2.z;
      fv[7] = w0 * e0.w + w1 * e1.w + w2 * e2.w;
      short8 o;
      #pragma unroll
      for (int e = 0; e < 8; e++) o[e] = f2bf(fv[e]);
      *(short8*)(dst + cc) = o;
    }
  }
}

// ---------------------------------------------------------------------------
// GEMM1 (R6 structure): a1[M][256](bf16) = [p1 | hi] @ W0^T.
// 128x256 tile, BK=32, double-buffered sA+sB. A: k<256 from p1 (f32->bf16
// register path), k>=256 from hi via cp16. B: 1024-chunk cp16 (prefetched
// one step ahead — R7 proved in-step B loads from L2 are latency-exposed).
// One barrier per k-step.
// ---------------------------------------------------------------------------
__global__ __launch_bounds__(256, 2)
void gemm1_kernel(const float* __restrict__ p1, const short* __restrict__ hi,
                  const short* __restrict__ Bw, const float* __restrict__ bias,
                  short* __restrict__ Cb, float* __restrict__ stats) {
  __shared__ __align__(16) short sA[2][128 * 32];
  __shared__ __align__(16) short sB[2][256 * 32];
  const int tid = threadIdx.x;
  const int lane = tid & 63;
  const int wave = tid >> 6;
  const int wm = wave & 1;
  const int wn = wave >> 1;
  const size_t mbase = (size_t)(blockIdx.x & 7) * N_
                     + (size_t)(blockIdx.x >> 3) * 128;

  #define STAGE_A(K0, BUF)                                                    \
    if ((K0) < D_) {                                                          \
      _Pragma("unroll")                                                       \
      for (int t = 0; t < 2; t++) {                                           \
        const int c = tid * 2 + t;                                            \
        const int r = c >> 2; const int sc = (c & 3) * 8;                     \
        const float* src = p1 + (mbase + r) * D_ + (K0) + sc;                 \
        const float4 va = *(const float4*)src;                                \
        const float4 vb = *(const float4*)(src + 4);                          \
        short8 o;                                                             \
        o[0] = f2bf(va.x); o[1] = f2bf(va.y); o[2] = f2bf(va.z);              \
        o[3] = f2bf(va.w); o[4] = f2bf(vb.x); o[5] = f2bf(vb.y);              \
        o[6] = f2bf(vb.z); o[7] = f2bf(vb.w);                                 \
        *(short8*)&sA[BUF][r * 32 + sc] = o;                                  \
      }                                                                       \
    } else {                                                                  \
      _Pragma("unroll")                                                       \
      for (int t = 0; t < 2; t++) {                                           \
        const int ca = wave * 128 + t * 64 + lane;                            \
        cp16(hi + (mbase + (ca >> 2)) * D_ + ((K0) - D_) + (ca & 3) * 8,      \
             &sA[BUF][(wave * 128 + t * 64) * 8]);                            \
      }                                                                       \
    }

  #define STAGE_B(K0, BUF)                                                    \
    _Pragma("unroll")                                                         \
    for (int t = 0; t < 4; t++) {                                             \
      const int cb = wave * 256 + t * 64 + lane;                              \
      cp16(Bw + (size_t)(cb >> 2) * K2D_ + (K0) + (cb & 3) * 8,               \
           &sB[BUF][(wave * 256 + t * 64) * 8]);                              \
    }

  f32x4 acc[4][8] = {};
  STAGE_A(0, 0);
  STAGE_B(0, 0);

  const int mr = lane & 15;
  const int ks = (lane >> 4) * 8;

  for (int k0 = 0, it = 0; k0 < K2D_; k0 += 32, it++) {
    __syncthreads();   // drains prev STAGE (vmcnt0 + lgkm) + WAR on LDS bufs
    const int kn = k0 + 32;
    if (kn < K2D_) {
      STAGE_A(kn, (it + 1) & 1);
      STAGE_B(kn, (it + 1) & 1);
    }

    short8 af[4], bfr[8];
    #pragma unroll
    for (int i = 0; i < 4; i++)
      af[i]  = *(const short8*)&sA[it & 1][(wm * 64 + i * 16 + mr) * 32 + ks];
    #pragma unroll
    for (int j = 0; j < 8; j++)
      bfr[j] = *(const short8*)&sB[it & 1][(wn * 128 + j * 16 + mr) * 32 + ks];
    #pragma unroll
    for (int i = 0; i < 4; i++)
      #pragma unroll
      for (int j = 0; j < 8; j++)
        acc[i][j] = __builtin_amdgcn_mfma_f32_16x16x32_bf16(af[i], bfr[j], acc[i][j], 0, 0, 0);
  }
  #undef STAGE_A
  #undef STAGE_B
  __syncthreads();   // all MFMA LDS reads done before sA reuse as sred

  // Epilogue: bf16 store + per-column (sum,sumsq) -> stats (bias excluded)
  const int cr = (lane >> 4) * 4;
  const int cc = lane & 15;
  float ps[8], ps2[8];
  #pragma unroll
  for (int j = 0; j < 8; j++) {
    const int col = wn * 128 + j * 16 + cc;
    const float bv = bias[col];
    float s = 0.f, s2 = 0.f;
    #pragma unroll
    for (int i = 0; i < 4; i++) {
      #pragma unroll
      for (int r = 0; r < 4; r++) {
        const float vv = acc[i][j][r];
        s += vv; s2 += vv * vv;
        const size_t row = mbase + wm * 64 + i * 16 + cr + r;
        Cb[row * C0_ + col] = f2bf(vv + bv);
      }
    }
    ps[j] = s; ps2[j] = s2;
  }
  #pragma unroll
  for (int j = 0; j < 8; j++) {
    ps[j]  += __shfl_xor(ps[j], 16);  ps[j]  += __shfl_xor(ps[j], 32);
    ps2[j] += __shfl_xor(ps2[j], 16); ps2[j] += __shfl_xor(ps2[j], 32);
  }
  float* sred = (float*)sA;   // reuse: 256 cols x {s,s2} = 2 KB
  if (wm == 1 && lane < 16) {
    #pragma unroll
    for (int j = 0; j < 8; j++) {
      const int c = wn * 128 + j * 16 + lane;
      sred[2 * c] = ps[j]; sred[2 * c + 1] = ps2[j];
    }
  }
  __syncthreads();
  if (wm == 0 && lane < 16) {
    #pragma unroll
    for (int j = 0; j < 8; j++) {
      const int c = wn * 128 + j * 16 + lane;
      atomicAdd(&stats[c],       ps[j]  + sred[2 * c]);
      atomicAdd(&stats[C0_ + c], ps2[j] + sred[2 * c + 1]);
    }
  }
}

// ---------------------------------------------------------------------------
// GEMM2 (R9: A register-prefetch): a2[M][128](bf16) = relu(bn(a1)) @ W1^T.
// R7 lesson applied in reverse: the old loop had dependent global A-loads
// issued and consumed inside the same k-iteration (latency exposed at 8
// waves/CU). Now next-iteration A-fragments are loaded BEFORE the current
// convert+MFMA block -> one full iteration of compute covers L3 latency.
// ---------------------------------------------------------------------------
__global__ __launch_bounds__(256, 2)
void gemm2_kernel(const short* __restrict__ A, const short* __restrict__ Bw,
                  const float* __restrict__ st1,
                  const float* __restrict__ b0, const float* __restrict__ g0,
                  const float* __restrict__ be0,
                  const float* __restrict__ bias,
                  short* __restrict__ Cb, float* __restrict__ stats) {
  __shared__ __align__(16) short sW[C1_ * SWP_];  // 128 x 264 shorts = 66 KB
  __shared__ float sred[3 * 256];
  __shared__ __align__(16) float sss[2 * C0_];
  const int tid = threadIdx.x;
  const int lane = tid & 63;
  const int wave = tid >> 6;
  const size_t mbase = (size_t)blockIdx.x * 128;

  // Preamble: per-block BN scale/shift from global stats.
  {
    const float inv = 1.0f / (float)M_;
    const float m0 = st1[tid] * inv;
    const float var = st1[C0_ + tid] * inv - m0 * m0;
    const float mean = m0 + b0[tid];
    const float sc = g0[tid] * rsqrtf(var + 1e-5f);
    sss[tid] = sc;
    sss[C0_ + tid] = be0[tid] - mean * sc;
  }

  // Load all of W1b into padded LDS (coalesced 16B reads, manual ds_write)
  #pragma unroll
  for (int i = 0; i < 16; i++) {
    const int flat = i * 256 + tid;       // 16B-block index, 0..4095
    const int n = flat >> 5;              // W1 row (32 blocks of 8 shorts each)
    const int kb = flat & 31;
    *(short8*)&sW[n * SWP_ + kb * 8] = *(const short8*)(Bw + (size_t)flat * 8);
  }
  __syncthreads();

  f32x4 acc[2][8] = {};
  const int mr = lane & 15;
  const int ksq = (lane >> 4) * 8;
  const short* Arow0 = A + (mbase + wave * 32 + 0 * 16 + mr) * C0_ + ksq;
  const short* Arow1 = A + (mbase + wave * 32 + 1 * 16 + mr) * C0_ + ksq;

  // Prefetch iteration 0's A-fragments.
  short8 avp0 = *(const short8*)(Arow0);
  short8 avp1 = *(const short8*)(Arow1);

  for (int k0 = 0; k0 < C0_; k0 += 32) {
    const int kk = k0 + ksq;
    // Consume prefetched, immediately issue next-iteration loads.
    short8 avc0 = avp0, avc1 = avp1;
    if (k0 + 32 < C0_) {
      avp0 = *(const short8*)(Arow0 + k0 + 32);
      avp1 = *(const short8*)(Arow1 + k0 + 32);
    }
    float4 sc0 = *(const float4*)&sss[kk];
    float4 sc1 = *(const float4*)&sss[kk + 4];
    float4 sh0 = *(const float4*)&sss[C0_ + kk];
    float4 sh1 = *(const float4*)&sss[C0_ + kk + 4];
    const float sc[8] = {sc0.x, sc0.y, sc0.z, sc0.w, sc1.x, sc1.y, sc1.z, sc1.w};
    const float sh[8] = {sh0.x, sh0.y, sh0.z, sh0.w, sh1.x, sh1.y, sh1.z, sh1.w};
    short8 af[2];
    {
      short8 o0, o1;
      #pragma unroll
      for (int e = 0; e < 8; e++) {
        float f0 = bf2f(avc0[e]) * sc[e] + sh[e];
        float f1 = bf2f(avc1[e]) * sc[e] + sh[e];
        o0[e] = f2bf(f0 > 0.f ? f0 : 0.f);
        o1[e] = f2bf(f1 > 0.f ? f1 : 0.f);
      }
      af[0] = o0; af[1] = o1;
    }
    short8 bf8[8];
    #pragma unroll
    for (int j = 0; j < 8; j++) bf8[j] = *(const short8*)&sW[(j * 16 + mr) * SWP_ + kk];
    #pragma unroll
    for (int i = 0; i < 2; i++)
      #pragma unroll
      for (int j = 0; j < 8; j++)
        acc[i][j] = __builtin_amdgcn_mfma_f32_16x16x32_bf16(af[i], bf8[j], acc[i][j], 0, 0, 0);
  }

  // Epilogue: bf16 store + per-column (sum,sumsq) -> stats
  const int cr = (lane >> 4) * 4;
  const int cc = lane & 15;
  float ps[8], ps2[8];
  #pragma unroll
  for (int j = 0; j < 8; j++) {
    const int col = j * 16 + cc;
    const float bv = bias[col];
    float s = 0.f, s2 = 0.f;
    #pragma unroll
    for (int i = 0; i < 2; i++) {
      #pragma unroll
      for (int r = 0; r < 4; r++) {
        const float vv = acc[i][j][r];
        s += vv; s2 += vv * vv;
        const size_t row = mbase + wave * 32 + i * 16 + cr + r;
        Cb[row * C1_ + col] = f2bf(vv + bv);
      }
    }
    ps[j] = s; ps2[j] = s2;
  }
  #pragma unroll
  for (int j = 0; j < 8; j++) {
    ps[j]  += __shfl_xor(ps[j], 16);  ps[j]  += __shfl_xor(ps[j], 32);
    ps2[j] += __shfl_xor(ps2[j], 16); ps2[j] += __shfl_xor(ps2[j], 32);
  }
  if (wave > 0 && lane < 16) {
    #pragma unroll
    for (int j = 0; j < 8; j++) {
      const int c = j * 16 + lane;
      sred[(wave - 1) * 256 + c]       = ps[j];
      sred[(wave - 1) * 256 + 128 + c] = ps2[j];
    }
  }
  __syncthreads();
  if (wave == 0 && lane < 16) {
    #pragma unroll
    for (int j = 0; j < 8; j++) {
      const int c = j * 16 + lane;
      float s  = ps[j]  + sred[c]       + sred[256 + c]       + sred[512 + c];
      float s2 = ps2[j] + sred[128 + c] + sred[256 + 128 + c] + sred[512 + 128 + c];
      atomicAdd(&stats[c],       s);
      atomicAdd(&stats[C1_ + c], s2);
    }
  }
}

// ---------------------------------------------------------------------------
// norm2 (+ stats preamble): out(f32) = relu(a2*sc + sh), 8 elems/thread
// ---------------------------------------------------------------------------
__global__ __launch_bounds__(256, 1)
void norm2_kernel(const short* __restrict__ a2, const float* __restrict__ st2,
                  const float* __restrict__ b1, const float* __restrict__ g1,
                  const float* __restrict__ be1, float* __restrict__ out) {
  __shared__ __align__(16) float sss[2 * C1_];
  const int tid = threadIdx.x;
  if (tid < C1_) {
    const float inv = 1.0f / (float)M_;
    const float m0 = st2[tid] * inv;
    const float var = st2[C1_ + tid] * inv - m0 * m0;
    const float mean = m0 + b1[tid];
    const float sc = g1[tid] * rsqrtf(var + 1e-5f);
    sss[tid] = sc;
    sss[C1_ + tid] = be1[tid] - mean * sc;
  }
  __syncthreads();
  const size_t t = (size_t)blockIdx.x * 256 + tid;
  const size_t base = t * 8;
  const int c = (int)(base & (C1_ - 1));
  short8 v8 = *(const short8*)(a2 + base);
  float vv[8];
  #pragma unroll
  for (int k = 0; k < 8; k++) {
    float v = bf2f(v8[k]) * sss[c + k] + sss[C1_ + c + k];
    vv[k] = v > 0.f ? v : 0.f;
  }
  *(float4*)(out + base)     = make_float4(vv[0], vv[1], vv[2], vv[3]);
  *(float4*)(out + base + 4) = make_float4(vv[4], vv[5], vv[6], vv[7]);
}

// ---------------------------------------------------------------------------
// Launch
// ---------------------------------------------------------------------------
extern "C" void kernel_launch(void* const* d_in, const int* in_sizes, int n_in,
                              void* d_out, int out_size, void* d_ws, size_t ws_size,
                              hipStream_t stream) {
  const float* xyz1 = (const float*)d_in[0];
  const float* xyz2 = (const float*)d_in[1];
  const float* pts1 = (const float*)d_in[2];
  const float* pts2 = (const float*)d_in[3];
  const float* relw = (const float*)d_in[4];
  const float* relb = (const float*)d_in[5];
  const float* W0   = (const float*)d_in[6];
  const float* b0   = (const float*)d_in[7];
  const float* g0   = (const float*)d_in[8];
  const float* be0  = (const float*)d_in[9];
  const float* W1   = (const float*)d_in[10];
  const float* b1   = (const float*)d_in[11];
  const float* g1   = (const float*)d_in[12];
  const float* be1  = (const float*)d_in[13];

  char* ws = (char*)d_ws;
  constexpr size_t W0B_OFF = 0;                                    // 256*512 bf16
  constexpr size_t W1B_OFF = W0B_OFF + (size_t)C0_ * K2D_ * 2;     // 128*256 bf16
  constexpr size_t XW_OFF  = W1B_OFF + (size_t)C1_ * C0_ * 2;      // B*4*S f32
  constexpr size_t HI_OFF  = XW_OFF + (size_t)B_ * 4 * S_ * 4;     // M*256 bf16 (33.5 MB)
  constexpr size_t A1_OFF  = HI_OFF + (size_t)M_ * D_ * 2;         // M*256 bf16
  constexpr size_t A2_OFF  = A1_OFF + (size_t)M_ * C0_ * 2;        // M*128 bf16
  constexpr size_t ST_OFF  = A2_OFF + (size_t)M_ * C1_ * 2;        // 768 f32

  short* W0b   = (short*)(ws + W0B_OFF);
  short* W1b   = (short*)(ws + W1B_OFF);
  float* xyz2p = (float*)(ws + XW_OFF);
  short* hi    = (short*)(ws + HI_OFF);
  short* a1    = (short*)(ws + A1_OFF);
  short* a2    = (short*)(ws + A2_OFF);
  float* st    = (float*)(ws + ST_OFF);   // stats1 = st, stats2 = st + 512
  float* outp  = (float*)d_out;

  convw_kernel<<<512, 256, 0, stream>>>(W0, W1, xyz2, W0b, W1b, xyz2p, st);
  topk_interp_kernel<<<B_ * (N_ / 64), 512, 0, stream>>>(xyz1, xyz2p, relw, relb, pts2, hi);

  gemm1_kernel<<<M_ / 128, 256, 0, stream>>>(pts1, hi, W0b, b0, a1, st);
  gemm2_kernel<<<M_ / 128, 256, 0, stream>>>(a1, W1b, st, b0, g0, be0, b1, a2, st + 512);
  norm2_kernel<<<(size_t)M_ * C1_ / 8 / 256, 256, 0, stream>>>(a2, st + 512, b1, g1, be1, outp);
}